// Round 8
// baseline (347.580 us; speedup 1.0000x reference)
//
#include <hip/hip_runtime.h>
#include <math.h>

// GIN forward, MI355X. Round 8 submission: dispatch-graph consolidation
// (9 launches, 0 API calls). Hot-kernel interiors identical to the 324us
// round-5 measurement; this build differs from round-6/7 only textually
// (artifact-hash bust after two container-level failures).

#define NHID 128
#define NFEAT 256
#define NCLASS 40

typedef __bf16 bf16x8 __attribute__((ext_vector_type(8)));
typedef __bf16 bf16x4 __attribute__((ext_vector_type(4)));
typedef float floatx4 __attribute__((ext_vector_type(4)));

// ===========================================================================
// Shared device helpers
// ===========================================================================

// 256-wide inclusive scan over LDS buffer sbuf (sbuf[tid] preloaded).
__device__ __forceinline__ void scan256(int* sbuf, int tid) {
    for (int off = 1; off < 256; off <<= 1) {
        int tmp = (tid >= off) ? sbuf[tid - off] : 0;
        __syncthreads();
        sbuf[tid] += tmp;
        __syncthreads();
    }
}

// MFMA GEMM core: out = relu(A @ W + b), N=128, split-precision bf16.
// MODE 0: A = fp32 Af[M][K] (input layer, K=256), hi/lo split in staging.
// MODE 1: A = bf16 hi/lo pair (K=128), pure copy staging.
// Tile 64x128, BK=64, XOR-swizzled LDS, 3 MFMAs per fragment.
template <int MODE>
__device__ __forceinline__ void gemm_body(
    char* smem, const float* __restrict__ Af, const __bf16* __restrict__ Ahi,
    const __bf16* __restrict__ Alo,
    const __bf16* __restrict__ Wthi, const __bf16* __restrict__ Wtlo,
    const float* __restrict__ bias, __bf16* __restrict__ Ohi,
    __bf16* __restrict__ Olo, int M, int K, int row0, int tid) {
    __bf16* sAhi = (__bf16*)smem;                // 64x64 = 8KB
    __bf16* sAlo = (__bf16*)(smem + 8192);       // 8KB
    __bf16* sWhi = (__bf16*)(smem + 16384);      // 128x64 = 16KB
    __bf16* sWlo = (__bf16*)(smem + 32768);      // 16KB

    int wave = tid >> 6;
    int l = tid & 63;
    int m16 = l & 15;
    int q = l >> 4;
    int axor = m16 & 7;
    int arow = wave * 16 + m16;

    floatx4 acc[8];
#pragma unroll
    for (int t = 0; t < 8; ++t) acc[t] = (floatx4){0.f, 0.f, 0.f, 0.f};

    for (int k0 = 0; k0 < K; k0 += 64) {
        // stage A tile (64 x 64)
#pragma unroll
        for (int it = 0; it < 2; ++it) {
            int lin = it * 2048 + tid * 8;
            int row = lin >> 6, k = lin & 63;
            int g = min(row0 + row, M - 1);
            int off = row * 64 + (((k >> 3) ^ (row & 7)) << 3);
            if (MODE == 0) {
                float4 v0 = *(const float4*)&Af[(size_t)g * K + k0 + k];
                float4 v1 = *(const float4*)&Af[(size_t)g * K + k0 + k + 4];
                float s[8] = {v0.x, v0.y, v0.z, v0.w, v1.x, v1.y, v1.z, v1.w};
                bf16x8 shi, slo;
#pragma unroll
                for (int j = 0; j < 8; ++j) {
                    __bf16 h = (__bf16)s[j];
                    shi[j] = h;
                    slo[j] = (__bf16)(s[j] - (float)h);
                }
                *(bf16x8*)(sAhi + off) = shi;
                *(bf16x8*)(sAlo + off) = slo;
            } else {
                *(bf16x8*)(sAhi + off) = *(const bf16x8*)&Ahi[(size_t)g * 128 + k0 + k];
                *(bf16x8*)(sAlo + off) = *(const bf16x8*)&Alo[(size_t)g * 128 + k0 + k];
            }
        }
        // stage W tile (128 x 64)
#pragma unroll
        for (int it = 0; it < 4; ++it) {
            int lin = it * 2048 + tid * 8;
            int n = lin >> 6, kk = lin & 63;
            int off = n * 64 + (((kk >> 3) ^ (n & 7)) << 3);
            *(bf16x8*)(sWhi + off) = *(const bf16x8*)&Wthi[(size_t)n * K + k0 + kk];
            *(bf16x8*)(sWlo + off) = *(const bf16x8*)&Wtlo[(size_t)n * K + k0 + kk];
        }
        __syncthreads();

#pragma unroll
        for (int s = 0; s < 2; ++s) {
            int sw = (((s * 4 + q) ^ axor) << 3);
            bf16x8 ahi = *(bf16x8*)(sAhi + arow * 64 + sw);
            bf16x8 alo = *(bf16x8*)(sAlo + arow * 64 + sw);
#pragma unroll
            for (int t = 0; t < 8; ++t) {
                int n = t * 16 + m16;
                bf16x8 bhi = *(bf16x8*)(sWhi + n * 64 + sw);
                bf16x8 blo = *(bf16x8*)(sWlo + n * 64 + sw);
                acc[t] = __builtin_amdgcn_mfma_f32_16x16x32_bf16(ahi, bhi, acc[t], 0, 0, 0);
                acc[t] = __builtin_amdgcn_mfma_f32_16x16x32_bf16(alo, bhi, acc[t], 0, 0, 0);
                acc[t] = __builtin_amdgcn_mfma_f32_16x16x32_bf16(ahi, blo, acc[t], 0, 0, 0);
            }
        }
        __syncthreads();
    }

    // epilogue: bias + relu -> fp32 LDS -> coalesced bf16 hi/lo stores
    float* eps = (float*)(smem + 16384);  // 64*128*4 = 32KB
#pragma unroll
    for (int t = 0; t < 8; ++t) {
        int col = t * 16 + m16;
        float bb = bias[col];
#pragma unroll
        for (int i = 0; i < 4; ++i) {
            int row = wave * 16 + q * 4 + i;
            eps[row * 128 + col] = fmaxf(acc[t][i] + bb, 0.f);
        }
    }
    __syncthreads();
#pragma unroll
    for (int it = 0; it < 8; ++it) {
        int lin = it * 1024 + tid * 4;
        int row = lin >> 7, col = lin & 127;
        int g = row0 + row;
        if (g < M) {
            float4 v = *(float4*)(eps + lin);
            bf16x4 hi, lo;
            float vv[4] = {v.x, v.y, v.z, v.w};
#pragma unroll
            for (int j = 0; j < 4; ++j) {
                __bf16 h = (__bf16)vv[j];
                hi[j] = h;
                lo[j] = (__bf16)(vv[j] - (float)h);
            }
            *(bf16x4*)&Ohi[(size_t)g * 128 + col] = hi;
            *(bf16x4*)&Olo[(size_t)g * 128 + col] = lo;
        }
    }
}

// ===========================================================================
// Dispatch 1: PREP -- block-range split of three independent jobs.
//   [0, eb4)        per-block partial bucket histograms (atomic-free global)
//   [eb4, eb4+320)  weight transpose+split (W_in 32768 + W_mlps 49152 elems)
//   [eb4+320]       zero cursor[256]; row_ptr[N] = E
// ===========================================================================
__global__ __launch_bounds__(256) void prep(
    const int* __restrict__ edst, int* __restrict__ phist, int E, int eb4,
    const float* __restrict__ Win, const float* __restrict__ Wmlps,
    __bf16* __restrict__ dInHi, __bf16* __restrict__ dInLo,
    __bf16* __restrict__ dMlHi, __bf16* __restrict__ dMlLo,
    int* __restrict__ cursor, int* __restrict__ row_ptr, int N) {
    __shared__ int lhist[256];
    int tid = threadIdx.x;
    int bid = blockIdx.x;
    if (bid < eb4) {
        lhist[tid] = 0;
        __syncthreads();
        int base = bid * 4096;
#pragma unroll
        for (int k = 0; k < 16; ++k) {
            int e = base + k * 256 + tid;
            if (e < E) atomicAdd(&lhist[edst[e] >> 8], 1);
        }
        __syncthreads();
        phist[bid * 256 + tid] = lhist[tid];
    } else if (bid < eb4 + 320) {
        const int TOT_IN = 128 * NFEAT;      // 32768
        const int TOT_ML = 3 * 128 * NHID;   // 49152
        int i = (bid - eb4) * 256 + tid;
        if (i < TOT_IN) {
            int n = i / NFEAT;
            int k = i - n * NFEAT;
            float v = Win[(size_t)k * 128 + n];
            __bf16 h = (__bf16)v;
            dInHi[i] = h;
            dInLo[i] = (__bf16)(v - (float)h);
        } else if (i < TOT_IN + TOT_ML) {
            int r = i - TOT_IN;
            int per = 128 * NHID;
            int l = r / per;
            int rr = r - l * per;
            int n = rr / NHID;
            int k = rr - n * NHID;
            float v = Wmlps[(size_t)l * per + (size_t)k * 128 + n];
            __bf16 h = (__bf16)v;
            dMlHi[r] = h;
            dMlLo[r] = (__bf16)(v - (float)h);
        }
    } else {
        cursor[tid] = 0;
        if (tid == 0) row_ptr[N] = E;
    }
}

// ===========================================================================
// Dispatch 2: SCATTER (inline redundant bucket scan per block).
// Sum partial hists -> exclusive scan -> bucket starts; then LDS-aggregated
// scatter claiming contiguous runs via cursor atomics.
// Record = (dst&255)<<16 | src  (valid since N <= 65536).
// ===========================================================================
__global__ __launch_bounds__(256) void scatter(const int* __restrict__ esrc,
                                               const int* __restrict__ edst,
                                               const int* __restrict__ phist,
                                               int* __restrict__ cursor,
                                               unsigned int* __restrict__ bdata,
                                               int E, int eb4) {
    __shared__ int sscan[256];
    __shared__ int sstart[256];
    __shared__ int lhist[256];
    __shared__ int lbase[256];
    int tid = threadIdx.x;
    int tot = 0;
    for (int p = 0; p < eb4; ++p) tot += phist[p * 256 + tid];
    sscan[tid] = tot;
    __syncthreads();
    scan256(sscan, tid);
    sstart[tid] = sscan[tid] - tot;
    lhist[tid] = 0;
    __syncthreads();

    int base = blockIdx.x * 4096;
    unsigned int recs[16];
    short bks[16];
    short lofs[16];
#pragma unroll
    for (int k = 0; k < 16; ++k) {
        int e = base + k * 256 + tid;
        bks[k] = -1;
        if (e < E) {
            int d = edst[e];
            int s = esrc[e];
            int b = d >> 8;
            recs[k] = ((unsigned int)(d & 255) << 16) | (unsigned int)s;
            bks[k] = (short)b;
            lofs[k] = (short)atomicAdd(&lhist[b], 1);
        }
    }
    __syncthreads();
    if (lhist[tid]) lbase[tid] = sstart[tid] + atomicAdd(&cursor[tid], lhist[tid]);
    __syncthreads();
#pragma unroll
    for (int k = 0; k < 16; ++k) {
        if (bks[k] >= 0) bdata[lbase[bks[k]] + lofs[k]] = recs[k];
    }
}

// ===========================================================================
// Dispatch 3: FINALIZE (blocks [0,nbuck)) || GEMM_IN (blocks [nbuck,nbuck+gb)).
// Both depend only on scatter's output; block-range split.
// ===========================================================================
__global__ __launch_bounds__(256) void fin_gemmin(
    const unsigned int* __restrict__ bdata, const int* __restrict__ phist,
    int eb4, int nbuck, int* __restrict__ row_ptr, int* __restrict__ srcs, int N,
    const float* __restrict__ Af,
    const __bf16* __restrict__ Wthi, const __bf16* __restrict__ Wtlo,
    const float* __restrict__ bias, __bf16* __restrict__ Ohi,
    __bf16* __restrict__ Olo) {
    __shared__ __align__(16) char smem[49152];
    int tid = threadIdx.x;
    if ((int)blockIdx.x < nbuck) {
        int* sscan = (int*)smem;           // 1KB scan buffer
        int* nhist = (int*)(smem + 1024);  // 1KB node histogram
        int* wcur  = (int*)(smem + 2048);  // 1KB write cursors
        int b = blockIdx.x;
        int tot = 0;
        for (int p = 0; p < eb4; ++p) tot += phist[p * 256 + tid];
        sscan[tid] = tot;
        __syncthreads();
        scan256(sscan, tid);
        int s0 = (b > 0) ? sscan[b - 1] : 0;
        int cnt = sscan[b] - s0;
        __syncthreads();
        nhist[tid] = 0;
        __syncthreads();
        for (int i = tid; i < cnt; i += 256) atomicAdd(&nhist[bdata[s0 + i] >> 16], 1);
        __syncthreads();
        int v0 = nhist[tid];
        __syncthreads();
        scan256(nhist, tid);
        int excl = nhist[tid] - v0;
        wcur[tid] = excl;
        int node = b * 256 + tid;
        if (node < N) row_ptr[node] = s0 + excl;
        __syncthreads();
        for (int i = tid; i < cnt; i += 256) {
            unsigned int r = bdata[s0 + i];
            int p = atomicAdd(&wcur[r >> 16], 1);
            srcs[s0 + p] = (int)(r & 0xffffu);
        }
    } else {
        int row0 = ((int)blockIdx.x - nbuck) * 64;
        gemm_body<0>(smem, Af, (const __bf16*)nullptr, (const __bf16*)nullptr,
                     Wthi, Wtlo, bias, Ohi, Olo, N, NFEAT, row0, tid);
    }
}

// ===========================================================================
// Fused aggregate: sum = h[node](hi+lo) + sum_{src in CSR} h_hi[src],
// written as bf16 hi/lo. One wave/node; row = 256B = 16 lanes x 16B; each
// gather instruction covers 4 edges; up to 16 edges (4 gathers) in flight.
// ===========================================================================
__global__ __launch_bounds__(256) void aggregate_fused(const __bf16* __restrict__ hhi,
                                                       const __bf16* __restrict__ hlo,
                                                       const int* __restrict__ row_ptr,
                                                       const int* __restrict__ srcs,
                                                       __bf16* __restrict__ ohi,
                                                       __bf16* __restrict__ olo, int N) {
    int tid = threadIdx.x;
    int node = blockIdx.x * 4 + (tid >> 6);
    if (node >= N) return;
    int lane = tid & 63;
    int g = lane >> 4;   // edge slot 0..3
    int c = lane & 15;   // 16B chunk (8 bf16 features)
    int beg = row_ptr[node];
    int end = row_ptr[node + 1];
    const bf16x8* hv = (const bf16x8*)hhi;

    bf16x8 selfhi = hv[(size_t)node * 16 + c];
    bf16x8 selflo = ((const bf16x8*)hlo)[(size_t)node * 16 + c];

    float a[8], b2[8];
#pragma unroll
    for (int j = 0; j < 8; ++j) { a[j] = 0.f; b2[j] = 0.f; }

    int i = beg;
    for (; i + 16 <= end; i += 16) {
        int s0 = __builtin_nontemporal_load(&srcs[i + g]);
        int s1 = __builtin_nontemporal_load(&srcs[i + 4 + g]);
        int s2 = __builtin_nontemporal_load(&srcs[i + 8 + g]);
        int s3 = __builtin_nontemporal_load(&srcs[i + 12 + g]);
        bf16x8 v0 = hv[(size_t)s0 * 16 + c];
        bf16x8 v1 = hv[(size_t)s1 * 16 + c];
        bf16x8 v2 = hv[(size_t)s2 * 16 + c];
        bf16x8 v3 = hv[(size_t)s3 * 16 + c];
#pragma unroll
        for (int j = 0; j < 8; ++j) {
            a[j] += (float)v0[j] + (float)v2[j];
            b2[j] += (float)v1[j] + (float)v3[j];
        }
    }
    for (; i + 8 <= end; i += 8) {
        int s0 = __builtin_nontemporal_load(&srcs[i + g]);
        int s1 = __builtin_nontemporal_load(&srcs[i + 4 + g]);
        bf16x8 v0 = hv[(size_t)s0 * 16 + c];
        bf16x8 v1 = hv[(size_t)s1 * 16 + c];
#pragma unroll
        for (int j = 0; j < 8; ++j) { a[j] += (float)v0[j]; b2[j] += (float)v1[j]; }
    }
    for (; i < end; i += 4) {
        if (i + g < end) {
            int s = __builtin_nontemporal_load(&srcs[i + g]);
            bf16x8 v = hv[(size_t)s * 16 + c];
#pragma unroll
            for (int j = 0; j < 8; ++j) a[j] += (float)v[j];
        }
    }
#pragma unroll
    for (int j = 0; j < 8; ++j) a[j] += b2[j];
#pragma unroll
    for (int j = 0; j < 8; ++j) a[j] += __shfl_xor(a[j], 16);
#pragma unroll
    for (int j = 0; j < 8; ++j) a[j] += __shfl_xor(a[j], 32);

    if (g == 0) {
        bf16x8 whi, wlo;
#pragma unroll
        for (int j = 0; j < 8; ++j) {
            float v = a[j] + (float)selfhi[j] + (float)selflo[j];
            __bf16 h = (__bf16)v;
            whi[j] = h;
            wlo[j] = (__bf16)(v - (float)h);
        }
        ((bf16x8*)ohi)[(size_t)node * 16 + c] = whi;
        ((bf16x8*)olo)[(size_t)node * 16 + c] = wlo;
    }
}

// ===========================================================================
// Mid GIN-layer GEMM (MODE 1 wrapper).
// ===========================================================================
__global__ __launch_bounds__(256) void gemm_layer(
    const __bf16* __restrict__ Ahi, const __bf16* __restrict__ Alo,
    const __bf16* __restrict__ Wthi, const __bf16* __restrict__ Wtlo,
    const float* __restrict__ bias, __bf16* __restrict__ Ohi,
    __bf16* __restrict__ Olo, int M) {
    __shared__ __align__(16) char smem[49152];
    gemm_body<1>(smem, (const float*)nullptr, Ahi, Alo, Wthi, Wtlo, bias,
                 Ohi, Olo, M, NHID, blockIdx.x * 64, threadIdx.x);
}

// ===========================================================================
// Final GIN-layer GEMM fused with output layer + log_softmax:
//   h' = relu(A @ W + b)  kept in fp32 LDS; logits = h' @ W_out + b_out;
//   out = log_softmax(logits).
// ===========================================================================
__global__ __launch_bounds__(256) void gemm_out(
    const __bf16* __restrict__ Ahi, const __bf16* __restrict__ Alo,
    const __bf16* __restrict__ Wthi, const __bf16* __restrict__ Wtlo,
    const float* __restrict__ bias,
    const float* __restrict__ Wout, const float* __restrict__ bout,
    float* __restrict__ out, int M) {
    __shared__ __align__(16) char smem[57344];
    __bf16* sAhi = (__bf16*)smem;                // 8KB
    __bf16* sAlo = (__bf16*)(smem + 8192);       // 8KB
    __bf16* sWhi = (__bf16*)(smem + 16384);      // 16KB
    __bf16* sWlo = (__bf16*)(smem + 32768);      // 16KB

    int tid = threadIdx.x;
    int row0 = blockIdx.x * 64;
    int wave = tid >> 6;
    int l = tid & 63;
    int m16 = l & 15;
    int q = l >> 4;
    int axor = m16 & 7;
    int arow = wave * 16 + m16;

    floatx4 acc[8];
#pragma unroll
    for (int t = 0; t < 8; ++t) acc[t] = (floatx4){0.f, 0.f, 0.f, 0.f};

    for (int k0 = 0; k0 < 128; k0 += 64) {
#pragma unroll
        for (int it = 0; it < 2; ++it) {
            int lin = it * 2048 + tid * 8;
            int row = lin >> 6, k = lin & 63;
            int g = min(row0 + row, M - 1);
            int off = row * 64 + (((k >> 3) ^ (row & 7)) << 3);
            *(bf16x8*)(sAhi + off) = *(const bf16x8*)&Ahi[(size_t)g * 128 + k0 + k];
            *(bf16x8*)(sAlo + off) = *(const bf16x8*)&Alo[(size_t)g * 128 + k0 + k];
        }
#pragma unroll
        for (int it = 0; it < 4; ++it) {
            int lin = it * 2048 + tid * 8;
            int n = lin >> 6, kk = lin & 63;
            int off = n * 64 + (((kk >> 3) ^ (n & 7)) << 3);
            *(bf16x8*)(sWhi + off) = *(const bf16x8*)&Wthi[(size_t)n * 128 + k0 + kk];
            *(bf16x8*)(sWlo + off) = *(const bf16x8*)&Wtlo[(size_t)n * 128 + k0 + kk];
        }
        __syncthreads();

#pragma unroll
        for (int s = 0; s < 2; ++s) {
            int sw = (((s * 4 + q) ^ axor) << 3);
            bf16x8 ahi = *(bf16x8*)(sAhi + arow * 64 + sw);
            bf16x8 alo = *(bf16x8*)(sAlo + arow * 64 + sw);
#pragma unroll
            for (int t = 0; t < 8; ++t) {
                int n = t * 16 + m16;
                bf16x8 bhi = *(bf16x8*)(sWhi + n * 64 + sw);
                bf16x8 blo = *(bf16x8*)(sWlo + n * 64 + sw);
                acc[t] = __builtin_amdgcn_mfma_f32_16x16x32_bf16(ahi, bhi, acc[t], 0, 0, 0);
                acc[t] = __builtin_amdgcn_mfma_f32_16x16x32_bf16(alo, bhi, acc[t], 0, 0, 0);
                acc[t] = __builtin_amdgcn_mfma_f32_16x16x32_bf16(ahi, blo, acc[t], 0, 0, 0);
            }
        }
        __syncthreads();
    }

    // epilogue A: bias + relu into fp32 LDS (stride 132 breaks bank aliasing)
    float* eps = (float*)smem;                    // 64*132*4 = 33792 B
    float* sWo = (float*)(smem + 34816);          // 128*40*4 = 20480 B
    float* sb  = (float*)(smem + 55296);          // 160 B
#pragma unroll
    for (int t = 0; t < 8; ++t) {
        int col = t * 16 + m16;
        float bb = bias[col];
#pragma unroll
        for (int i = 0; i < 4; ++i) {
            int row = wave * 16 + q * 4 + i;
            eps[row * 132 + col] = fmaxf(acc[t][i] + bb, 0.f);
        }
    }
    for (int i = tid; i < 128 * NCLASS; i += 256) sWo[i] = Wout[i];
    if (tid < NCLASS) sb[tid] = bout[tid];
    __syncthreads();

    // epilogue B: logits + log_softmax. 4 lanes/row, 10 classes/lane.
    int r = tid >> 2;
    int cg = tid & 3;
    float z[10];
#pragma unroll
    for (int j = 0; j < 10; ++j) z[j] = sb[cg * 10 + j];
    for (int k = 0; k < 128; ++k) {
        float a = eps[r * 132 + k];
#pragma unroll
        for (int j = 0; j < 10; ++j) z[j] += a * sWo[k * NCLASS + cg * 10 + j];
    }
    float m = z[0];
#pragma unroll
    for (int j = 1; j < 10; ++j) m = fmaxf(m, z[j]);
    m = fmaxf(m, __shfl_xor(m, 1));
    m = fmaxf(m, __shfl_xor(m, 2));
    float s = 0.f;
#pragma unroll
    for (int j = 0; j < 10; ++j) s += expf(z[j] - m);
    s += __shfl_xor(s, 1);
    s += __shfl_xor(s, 2);
    float lse = m + logf(s);
    int row = row0 + r;
    if (row < M) {
#pragma unroll
        for (int j = 0; j < 10; ++j) out[(size_t)row * NCLASS + cg * 10 + j] = z[j] - lse;
    }
}

// ===========================================================================
extern "C" void kernel_launch(void* const* d_in, const int* in_sizes, int n_in,
                              void* d_out, int out_size, void* d_ws, size_t ws_size,
                              hipStream_t stream) {
    const float* x      = (const float*)d_in[0];
    const int*   esrc   = (const int*)d_in[1];
    const int*   edst   = (const int*)d_in[2];
    const float* W_in   = (const float*)d_in[3];
    const float* b_in   = (const float*)d_in[4];
    const float* W_mlps = (const float*)d_in[5];
    const float* b_mlps = (const float*)d_in[6];
    const float* W_out  = (const float*)d_in[7];
    const float* b_out  = (const float*)d_in[8];
    float* out = (float*)d_out;

    int N = in_sizes[0] / NFEAT;  // 50000
    int E = in_sizes[1];          // 800000
    int nbuck = (N + 255) >> 8;   // 196
    int eb4 = (E + 4095) / 4096;  // 196

    // workspace carve (~81 MB of the 256 MiB workspace)
    char* ws = (char*)d_ws;
    size_t hb = (((size_t)N * NHID * sizeof(__bf16)) + 255) & ~(size_t)255;  // 12.8MB
    __bf16* h_hi_a = (__bf16*)ws;
    __bf16* h_lo_a = (__bf16*)(ws + hb);
    __bf16* h_hi_b = (__bf16*)(ws + 2 * hb);
    __bf16* h_lo_b = (__bf16*)(ws + 3 * hb);
    __bf16* sum_hi = (__bf16*)(ws + 4 * hb);
    __bf16* sum_lo = (__bf16*)(ws + 5 * hb);
    // bdata aliases sum_hi's slot (used only during CSR build, before any agg)
    unsigned int* bdata = (unsigned int*)(ws + 4 * hb);
    char* ip = ws + 6 * hb;
    int* row_ptr = (int*)ip;  ip += (((size_t)(N + 1) * 4) + 255) & ~(size_t)255;
    int* srcs    = (int*)ip;  ip += (((size_t)E * 4) + 255) & ~(size_t)255;
    int* phist   = (int*)ip;  ip += (size_t)eb4 * 256 * 4;       // ~200KB
    int* cursor  = (int*)ip;  ip += 1024;
    __bf16* Wt_in_hi   = (__bf16*)ip;  ip += 128 * NFEAT * 2;
    __bf16* Wt_in_lo   = (__bf16*)ip;  ip += 128 * NFEAT * 2;
    __bf16* Wt_mlps_hi = (__bf16*)ip;  ip += 3 * 128 * NHID * 2;
    __bf16* Wt_mlps_lo = (__bf16*)ip;  ip += 3 * 128 * NHID * 2;

    int gb = (N + 63) / 64;

    // 1: prep (hist partials || weight transpose || cursor zero)
    prep<<<eb4 + 320 + 1, 256, 0, stream>>>(edst, phist, E, eb4, W_in, W_mlps,
                                            Wt_in_hi, Wt_in_lo, Wt_mlps_hi, Wt_mlps_lo,
                                            cursor, row_ptr, N);
    // 2: scatter (inline scan)
    scatter<<<eb4, 256, 0, stream>>>(esrc, edst, phist, cursor, bdata, E, eb4);
    // 3: finalize || input-layer GEMM
    fin_gemmin<<<nbuck + gb, 256, 0, stream>>>(bdata, phist, eb4, nbuck, row_ptr, srcs, N,
                                               x, Wt_in_hi, Wt_in_lo, b_in, h_hi_a, h_lo_a);

    // 4-7: GIN layers 0,1 (aggregate + gemm)
    __bf16* cur_hi = h_hi_a; __bf16* cur_lo = h_lo_a;
    __bf16* nxt_hi = h_hi_b; __bf16* nxt_lo = h_lo_b;
    for (int i = 0; i < 2; ++i) {
        aggregate_fused<<<(N + 3) / 4, 256, 0, stream>>>(cur_hi, cur_lo, row_ptr, srcs,
                                                         sum_hi, sum_lo, N);
        gemm_layer<<<gb, 256, 0, stream>>>(
            sum_hi, sum_lo,
            Wt_mlps_hi + (size_t)i * 128 * NHID, Wt_mlps_lo + (size_t)i * 128 * NHID,
            b_mlps + (size_t)i * NHID, nxt_hi, nxt_lo, N);
        __bf16* t;
        t = cur_hi; cur_hi = nxt_hi; nxt_hi = t;
        t = cur_lo; cur_lo = nxt_lo; nxt_lo = t;
    }

    // 8-9: GIN layer 2 fused with output layer + log_softmax
    aggregate_fused<<<(N + 3) / 4, 256, 0, stream>>>(cur_hi, cur_lo, row_ptr, srcs,
                                                     sum_hi, sum_lo, N);
    gemm_out<<<gb, 256, 0, stream>>>(sum_hi, sum_lo,
                                     Wt_mlps_hi + (size_t)2 * 128 * NHID,
                                     Wt_mlps_lo + (size_t)2 * 128 * NHID,
                                     b_mlps + (size_t)2 * NHID,
                                     W_out, b_out, out, N);
}